// Round 6
// baseline (750.637 us; speedup 1.0000x reference)
//
#include <hip/hip_runtime.h>
#include <hip/hip_bf16.h>

typedef __bf16 bf8 __attribute__((ext_vector_type(8)));
typedef float f4 __attribute__((ext_vector_type(4)));
typedef unsigned short u16;
typedef unsigned int u32;

#define B_ 4
#define P_ 2048
#define D_ 768
#define H_ 12
#define HD_ 64
#define PT_ 16
// scale * log2(e): exp(s*0.125) = exp2(s * 0.18033688)
#define EXPC_ 0.18033688011112042f

typedef const __attribute__((address_space(1))) void gvoid;
typedef __attribute__((address_space(3))) void lvoid;

__device__ __forceinline__ void gl_lds16(const u16* g, u16* l) {
  __builtin_amdgcn_global_load_lds((gvoid*)g, (lvoid*)l, 16, 0, 0);
}

__device__ __forceinline__ u16 f2bf(float f) {  // RNE
  union { float f; u32 u; } c; c.f = f;
  u32 u = c.u;
  u += 0x7fffu + ((u >> 16) & 1u);
  return (u16)(u >> 16);
}

__device__ __forceinline__ float bf2f(u16 v) {
  union { u32 u; float f; } c; c.u = (u32)v << 16; return c.f;
}

__device__ __forceinline__ uint2 pack4(f4 v) {  // truncating 4xf32 -> 4xbf16
  union { float f; u32 u; } a, b, c, d;
  a.f = v[0]; b.f = v[1]; c.f = v[2]; d.f = v[3];
  uint2 r;
  r.x = (a.u >> 16) | (b.u & 0xffff0000u);
  r.y = (c.u >> 16) | (d.u & 0xffff0000u);
  return r;
}

__device__ __forceinline__ f4 unpack4(ushort4 v) {
  f4 r;
  r[0] = bf2f(v.x); r[1] = bf2f(v.y); r[2] = bf2f(v.z); r[3] = bf2f(v.w);
  return r;
}

__device__ __forceinline__ f4 mfma16(bf8 a, bf8 b, f4 c) {
  return __builtin_amdgcn_mfma_f32_16x16x32_bf16(a, b, c, 0, 0, 0);
}

#define ZERO44(acc)                    \
  {                                    \
    f4 z_ = {0.f, 0.f, 0.f, 0.f};      \
    for (int i_ = 0; i_ < 4; ++i_)     \
      for (int j_ = 0; j_ < 4; ++j_)   \
        acc[i_][j_] = z_;              \
  }

// ---------------- transpose-cast fp32 (R,C) -> bf16 (C,R) ----------------
__global__ __launch_bounds__(256) void tcast_k(const float* __restrict__ src,
                                               u16* __restrict__ dst, int R, int C) {
  __shared__ float t[32][33];
  int c0 = blockIdx.x * 32, r0 = blockIdx.y * 32;
  int tx = threadIdx.x & 31, ty = threadIdx.x >> 5;
  #pragma unroll
  for (int i = 0; i < 32; i += 8) {
    int r = r0 + ty + i, c = c0 + tx;
    t[ty + i][tx] = (r < R && c < C) ? src[(size_t)r * C + c] : 0.f;
  }
  __syncthreads();
  #pragma unroll
  for (int i = 0; i < 32; i += 8) {
    int c = c0 + ty + i, r = r0 + tx;
    if (c < C && r < R) dst[(size_t)c * R + r] = f2bf(t[tx][ty + i]);
  }
}

// ---------------- layernorm fp32 -> bf16 ----------------
__global__ __launch_bounds__(256) void ln_k(const float* __restrict__ x,
                                            const float* __restrict__ g,
                                            const float* __restrict__ b,
                                            u16* __restrict__ out) {
  int row = blockIdx.x;
  const float* xr = x + (size_t)row * D_;
  float v0 = xr[threadIdx.x], v1 = xr[threadIdx.x + 256], v2 = xr[threadIdx.x + 512];
  float s = v0 + v1 + v2;
  float s2 = v0 * v0 + v1 * v1 + v2 * v2;
  #pragma unroll
  for (int o = 32; o > 0; o >>= 1) {
    s += __shfl_down(s, o, 64);
    s2 += __shfl_down(s2, o, 64);
  }
  __shared__ float a[4], a2[4];
  int wv = threadIdx.x >> 6;
  if ((threadIdx.x & 63) == 0) { a[wv] = s; a2[wv] = s2; }
  __syncthreads();
  s = a[0] + a[1] + a[2] + a[3];
  s2 = a2[0] + a2[1] + a2[2] + a2[3];
  float mean = s * (1.f / 768.f);
  float var = s2 * (1.f / 768.f) - mean * mean;
  float rstd = rsqrtf(var + 1e-5f);
  u16* orow = out + (size_t)row * D_;
  float vv[3] = {v0, v1, v2};
  #pragma unroll
  for (int j = 0; j < 3; ++j) {
    int i = threadIdx.x + j * 256;
    orow[i] = f2bf((vv[j] - mean) * rstd * g[i] + b[i]);
  }
}

// ============ staged 128x128 GEMM core (m97 pattern), K-stride 32 ============
template <int K>
__device__ __forceinline__ void staged_core(const u16* __restrict__ Ab,
                                            const u16* __restrict__ Bb,
                                            u16* As, u16* Bs, f4 acc[4][4]) {
  const int wave = threadIdx.x >> 6, lane = threadIdx.x & 63;
  const int l15 = lane & 15, quad = lane >> 4;
  const int lrow = lane >> 2;
  const int lcol = (lane & 3) * 8;
  const int mw = (wave & 1) * 64, nw = (wave >> 1) * 64;
  for (int k0 = 0; k0 < K; k0 += 32) {
    const u16* ga = Ab + (size_t)(wave * 32 + lrow) * K + k0 + lcol;
    gl_lds16(ga, &As[(wave * 32) * 32]);
    gl_lds16(ga + (size_t)16 * K, &As[(wave * 32 + 16) * 32]);
    const u16* gb = Bb + (size_t)(wave * 32 + lrow) * K + k0 + lcol;
    gl_lds16(gb, &Bs[(wave * 32) * 32]);
    gl_lds16(gb + (size_t)16 * K, &Bs[(wave * 32 + 16) * 32]);
    __syncthreads();
    bf8 a[4], b[4];
    #pragma unroll
    for (int mt = 0; mt < 4; ++mt)
      a[mt] = *reinterpret_cast<const bf8*>(&As[(mw + mt * 16 + l15) * 32 + quad * 8]);
    #pragma unroll
    for (int nt = 0; nt < 4; ++nt)
      b[nt] = *reinterpret_cast<const bf8*>(&Bs[(nw + nt * 16 + l15) * 32 + quad * 8]);
    #pragma unroll
    for (int mt = 0; mt < 4; ++mt)
      #pragma unroll
      for (int nt = 0; nt < 4; ++nt)
        acc[mt][nt] = mfma16(a[mt], b[nt], acc[mt][nt]);
    __syncthreads();
  }
}

// ---------------- QKV GEMM staged ----------------
__global__ __launch_bounds__(256) void gemm_qkv_k(const u16* __restrict__ hln,
                                                  const u16* __restrict__ wT,
                                                  const float* __restrict__ bias,
                                                  u16* __restrict__ Q, u16* __restrict__ Km,
                                                  u16* __restrict__ Vt) {
  __shared__ u16 As[128 * 32], Bs[128 * 32];
  int m0 = blockIdx.y * 128, n0 = blockIdx.x * 128;
  f4 acc[4][4];
  ZERO44(acc);
  staged_core<768>(hln + (size_t)m0 * 768, wT + (size_t)n0 * 768, As, Bs, acc);
  int wave = threadIdx.x >> 6, lane = threadIdx.x & 63, l15 = lane & 15, quad = lane >> 4;
  int mW = m0 + (wave & 1) * 64, nW = n0 + (wave >> 1) * 64;
  #pragma unroll
  for (int mt = 0; mt < 4; ++mt)
    #pragma unroll
    for (int nt = 0; nt < 4; ++nt)
      #pragma unroll
      for (int r = 0; r < 4; ++r) {
        int m = mW + mt * 16 + quad * 4 + r;
        int n = nW + nt * 16 + l15;
        float v = acc[mt][nt][r] + bias[n];
        u16 bv = f2bf(v);
        int b = m >> 11, p = m & 2047;
        int which = n / 768, hn = n % 768;
        int h = hn >> 6, d = hn & 63;
        if (which == 0)
          Q[((size_t)(b * H_ + h) * P_ + p) * HD_ + d] = bv;
        else if (which == 1)
          Km[((size_t)(b * H_ + h) * P_ + p) * HD_ + d] = bv;
        else
          Vt[((size_t)(b * H_ + h) * HD_ + d) * P_ + p] = bv;
      }
}

// ---------------- FC1 GEMM staged + exact GELU ----------------
__global__ __launch_bounds__(256) void gemm_fc1_k(const u16* __restrict__ A,
                                                  const u16* __restrict__ wT,
                                                  const float* __restrict__ bias,
                                                  u16* __restrict__ out) {
  __shared__ u16 As[128 * 32], Bs[128 * 32];
  int m0 = blockIdx.y * 128, n0 = blockIdx.x * 128;
  f4 acc[4][4];
  ZERO44(acc);
  staged_core<768>(A + (size_t)m0 * 768, wT + (size_t)n0 * 768, As, Bs, acc);
  int wave = threadIdx.x >> 6, lane = threadIdx.x & 63, l15 = lane & 15, quad = lane >> 4;
  int mW = m0 + (wave & 1) * 64, nW = n0 + (wave >> 1) * 64;
  #pragma unroll
  for (int mt = 0; mt < 4; ++mt)
    #pragma unroll
    for (int nt = 0; nt < 4; ++nt)
      #pragma unroll
      for (int r = 0; r < 4; ++r) {
        int m = mW + mt * 16 + quad * 4 + r;
        int n = nW + nt * 16 + l15;
        float v = acc[mt][nt][r] + bias[n];
        v = 0.5f * v * (1.f + erff(v * 0.70710678f));
        out[(size_t)m * 3072 + n] = f2bf(v);
      }
}

// ---------------- FC2 GEMM staged (BM=128, BN=64), +bias +residual -> fp32 ----------------
__global__ __launch_bounds__(256) void gemm_fc2_k(const u16* __restrict__ A,
                                                  const u16* __restrict__ wT,
                                                  const float* __restrict__ bias,
                                                  const float* __restrict__ resid,
                                                  float* __restrict__ out) {
  __shared__ u16 As[128 * 32], Bs[64 * 32];
  int wave = threadIdx.x >> 6, lane = threadIdx.x & 63, l15 = lane & 15, quad = lane >> 4;
  int lrow = lane >> 2, lcol = (lane & 3) * 8;
  int m0 = blockIdx.y * 128, n0 = blockIdx.x * 64;
  const u16* Ab = A + (size_t)m0 * 3072;
  const u16* Bb = wT + (size_t)n0 * 3072;
  int mw = (wave & 1) * 64, nw = (wave >> 1) * 32;
  f4 acc[4][2];
  #pragma unroll
  for (int i = 0; i < 4; ++i)
    #pragma unroll
    for (int j = 0; j < 2; ++j) acc[i][j] = f4{0.f, 0.f, 0.f, 0.f};
  for (int k0 = 0; k0 < 3072; k0 += 32) {
    const u16* ga = Ab + (size_t)(wave * 32 + lrow) * 3072 + k0 + lcol;
    gl_lds16(ga, &As[(wave * 32) * 32]);
    gl_lds16(ga + (size_t)16 * 3072, &As[(wave * 32 + 16) * 32]);
    const u16* gb = Bb + (size_t)(wave * 16 + lrow) * 3072 + k0 + lcol;
    gl_lds16(gb, &Bs[(wave * 16) * 32]);
    __syncthreads();
    bf8 a[4], b[2];
    #pragma unroll
    for (int mt = 0; mt < 4; ++mt)
      a[mt] = *reinterpret_cast<const bf8*>(&As[(mw + mt * 16 + l15) * 32 + quad * 8]);
    #pragma unroll
    for (int nt = 0; nt < 2; ++nt)
      b[nt] = *reinterpret_cast<const bf8*>(&Bs[(nw + nt * 16 + l15) * 32 + quad * 8]);
    #pragma unroll
    for (int mt = 0; mt < 4; ++mt)
      #pragma unroll
      for (int nt = 0; nt < 2; ++nt)
        acc[mt][nt] = mfma16(a[mt], b[nt], acc[mt][nt]);
    __syncthreads();
  }
  int mW = m0 + mw, nW = n0 + nw;
  #pragma unroll
  for (int mt = 0; mt < 4; ++mt)
    #pragma unroll
    for (int nt = 0; nt < 2; ++nt)
      #pragma unroll
      for (int r = 0; r < 4; ++r) {
        int m = mW + mt * 16 + quad * 4 + r;
        int n = nW + nt * 16 + l15;
        size_t idx = (size_t)m * 768 + n;
        out[idx] = acc[mt][nt][r] + bias[n] + resid[idx];
      }
}

// ======== fused attention: all 12 heads per block, softmax over heads ========
// Block = (pt: 16 p-rows, b); 512 blocks = 2/CU. 768 threads = 12 waves = 12 heads.
// Double-buffered E -> 2 barriers per q-tile.
__global__ __launch_bounds__(768) void attn_fused_k(const u16* __restrict__ Q,
                                                    const u16* __restrict__ Km,
                                                    const u16* __restrict__ Vt,
                                                    const float* __restrict__ xin,
                                                    float* __restrict__ x2) {
  int pt = blockIdx.x, b = blockIdx.y;
  int w = threadIdx.x >> 6;  // wave == head
  int lane = threadIdx.x & 63, l15 = lane & 15, quad = lane >> 4;
  __shared__ __align__(16) u16 E2[2][12][PT_][72];  // 2 x 27.6 KB

  const u16* Qp = Q + ((size_t)(b * H_ + w) * P_ + pt * PT_) * HD_;
  const u16* Kbase = Km + (size_t)(b * H_ + w) * P_ * HD_;
  const u16* Vbase = Vt + (size_t)(b * H_ + w) * HD_ * P_;

  // Q fragments for this wave's head, 16 p-rows (persist across all q-tiles)
  bf8 qf[2];
  #pragma unroll
  for (int ks = 0; ks < 2; ++ks)
    qf[ks] = *reinterpret_cast<const bf8*>(Qp + (size_t)l15 * HD_ + ks * 32 + quad * 8);

  f4 oacc[4];  // O^T: d (4x16) x p (16)
  #pragma unroll
  for (int i = 0; i < 4; ++i) oacc[i] = f4{0.f, 0.f, 0.f, 0.f};

  for (int qt = 0; qt < P_ / 64; ++qt) {
    u16(*E)[PT_][72] = E2[qt & 1];
    const u16* Kp = Kbase + (size_t)qt * 64 * HD_;
    // --- S^T + exp -> E[w]: lane value (mt,r): q = mt*16+quad*4+r, p = l15 ---
    f4 s[4];
    #pragma unroll
    for (int i = 0; i < 4; ++i) s[i] = f4{0.f, 0.f, 0.f, 0.f};
    #pragma unroll
    for (int mt = 0; mt < 4; ++mt) {
      bf8 kf0 = *reinterpret_cast<const bf8*>(Kp + (size_t)(mt * 16 + l15) * HD_ + quad * 8);
      bf8 kf1 = *reinterpret_cast<const bf8*>(Kp + (size_t)(mt * 16 + l15) * HD_ + 32 + quad * 8);
      s[mt] = mfma16(kf0, qf[0], s[mt]);
      s[mt] = mfma16(kf1, qf[1], s[mt]);
    }
    #pragma unroll
    for (int mt = 0; mt < 4; ++mt) {
      f4 e;
      #pragma unroll
      for (int r = 0; r < 4; ++r) e[r] = __builtin_amdgcn_exp2f(s[mt][r] * EXPC_);
      *reinterpret_cast<uint2*>(&E[w][l15][mt * 16 + quad * 4]) = pack4(e);
    }
    __syncthreads();
    // --- D = sum_h E; E <- E * rcp(D), in place (threads 0..255, 1 f4 each) ---
    if (threadIdx.x < 256) {
      int p = threadIdx.x >> 4, q0 = (threadIdx.x & 15) * 4;
      ushort4 eh[12];
      f4 sum = {0.f, 0.f, 0.f, 0.f};
      #pragma unroll
      for (int h = 0; h < 12; ++h) {
        eh[h] = *reinterpret_cast<const ushort4*>(&E[h][p][q0]);
        sum += unpack4(eh[h]);
      }
      f4 rc;
      #pragma unroll
      for (int c = 0; c < 4; ++c) rc[c] = __builtin_amdgcn_rcpf(sum[c]);
      #pragma unroll
      for (int h = 0; h < 12; ++h)
        *reinterpret_cast<uint2*>(&E[h][p][q0]) = pack4(unpack4(eh[h]) * rc);
    }
    __syncthreads();
    // --- O^T += V^T-frag @ A-frag (A rows = p = l15) ---
    #pragma unroll
    for (int ks = 0; ks < 2; ++ks) {
      bf8 af = *reinterpret_cast<const bf8*>(&E[w][l15][ks * 32 + quad * 8]);
      #pragma unroll
      for (int dt = 0; dt < 4; ++dt) {
        bf8 vf = *reinterpret_cast<const bf8*>(Vbase + (size_t)(dt * 16 + l15) * P_ +
                                               qt * 64 + ks * 32 + quad * 8);
        oacc[dt] = mfma16(vf, af, oacc[dt]);
      }
    }
    // no trailing barrier: next tile writes the other E buffer
  }
  __syncthreads();
  // --- O^T (bf16) -> LDS: row p=l15, col d=dt*16+quad*4 ---
  #pragma unroll
  for (int dt = 0; dt < 4; ++dt)
    *reinterpret_cast<uint2*>(&E2[0][w][l15][dt * 16 + quad * 4]) = pack4(oacc[dt]);
  __syncthreads();
  // --- coalesced +residual write: 16 p-rows x 768 cols ---
  int m = threadIdx.x % 48, p = threadIdx.x / 48;  // 48 col-chunks of 16
  int h = m >> 2, d0 = (m & 3) * 16;
  size_t go = ((size_t)(b * P_) + pt * PT_ + p) * D_ + h * 64 + d0;
  #pragma unroll
  for (int j = 0; j < 4; ++j) {
    f4 o = unpack4(*reinterpret_cast<const ushort4*>(&E2[0][h][p][d0 + j * 4]));
    f4 xv = *reinterpret_cast<const f4*>(xin + go + j * 4);
    *reinterpret_cast<f4*>(x2 + go + j * 4) = o + xv;
  }
}

extern "C" void kernel_launch(void* const* d_in, const int* in_sizes, int n_in,
                              void* d_out, int out_size, void* d_ws, size_t ws_size,
                              hipStream_t stream) {
  const float* x = (const float*)d_in[0];
  const float* ln1w = (const float*)d_in[1];
  const float* ln1b = (const float*)d_in[2];
  const float* wqkv = (const float*)d_in[3];
  const float* bqkv = (const float*)d_in[4];
  const float* ln2w = (const float*)d_in[5];
  const float* ln2b = (const float*)d_in[6];
  const float* wfc1 = (const float*)d_in[7];
  const float* bfc1 = (const float*)d_in[8];
  const float* wfc2 = (const float*)d_in[9];
  const float* bfc2 = (const float*)d_in[10];
  float* out = (float*)d_out;

  char* ws = (char*)d_ws;
  size_t off = 0;
  auto alloc = [&](size_t bytes) -> void* {
    void* p = ws + off;
    off += (bytes + 255) & ~(size_t)255;
    return p;
  };
  u16* hln = (u16*)alloc((size_t)8192 * 768 * 2);
  u16* wqkvT = (u16*)alloc((size_t)2304 * 768 * 2);
  u16* wfc1T = (u16*)alloc((size_t)3072 * 768 * 2);
  u16* wfc2T = (u16*)alloc((size_t)768 * 3072 * 2);
  u16* Qb = (u16*)alloc((size_t)B_ * H_ * P_ * HD_ * 2);
  u16* Kb = (u16*)alloc((size_t)B_ * H_ * P_ * HD_ * 2);
  u16* Vtb = (u16*)alloc((size_t)B_ * H_ * HD_ * P_ * 2);
  float* x2 = (float*)alloc((size_t)8192 * 768 * 4);
  u16* g = (u16*)alloc((size_t)8192 * 3072 * 2);

  tcast_k<<<dim3(72, 24), 256, 0, stream>>>(wqkv, wqkvT, 768, 2304);
  tcast_k<<<dim3(96, 24), 256, 0, stream>>>(wfc1, wfc1T, 768, 3072);
  tcast_k<<<dim3(24, 96), 256, 0, stream>>>(wfc2, wfc2T, 3072, 768);
  ln_k<<<8192, 256, 0, stream>>>(x, ln1w, ln1b, hln);
  gemm_qkv_k<<<dim3(18, 64), 256, 0, stream>>>(hln, wqkvT, bqkv, Qb, Kb, Vtb);
  attn_fused_k<<<dim3(128, 4), 768, 0, stream>>>(Qb, Kb, Vtb, x, x2);
  ln_k<<<8192, 256, 0, stream>>>(x2, ln2w, ln2b, hln);
  gemm_fc1_k<<<dim3(24, 64), 256, 0, stream>>>(hln, wfc1T, bfc1, g);
  gemm_fc2_k<<<dim3(12, 64), 256, 0, stream>>>(g, wfc2T, bfc2, x2, out);
}

// Round 7
// 490.188 us; speedup vs baseline: 1.5313x; 1.5313x over previous
//
#include <hip/hip_runtime.h>
#include <hip/hip_bf16.h>

typedef __bf16 bf8 __attribute__((ext_vector_type(8)));
typedef float f4 __attribute__((ext_vector_type(4)));
typedef unsigned short u16;
typedef unsigned int u32;

#define B_ 4
#define P_ 2048
#define D_ 768
#define H_ 12
#define HD_ 64
// scale * log2(e): exp(s*0.125) = exp2(s * 0.18033688)
#define EXPC_ 0.18033688011112042f

typedef const __attribute__((address_space(1))) void gvoid;
typedef __attribute__((address_space(3))) void lvoid;

__device__ __forceinline__ void gl_lds16(const u16* g, u16* l) {
  __builtin_amdgcn_global_load_lds((gvoid*)g, (lvoid*)l, 16, 0, 0);
}

__device__ __forceinline__ u16 f2bf(float f) {  // RNE
  union { float f; u32 u; } c; c.f = f;
  u32 u = c.u;
  u += 0x7fffu + ((u >> 16) & 1u);
  return (u16)(u >> 16);
}

__device__ __forceinline__ float bf2f(u16 v) {
  union { u32 u; float f; } c; c.u = (u32)v << 16; return c.f;
}

__device__ __forceinline__ uint2 pack4(f4 v) {  // truncating 4xf32 -> 4xbf16
  union { float f; u32 u; } a, b, c, d;
  a.f = v[0]; b.f = v[1]; c.f = v[2]; d.f = v[3];
  uint2 r;
  r.x = (a.u >> 16) | (b.u & 0xffff0000u);
  r.y = (c.u >> 16) | (d.u & 0xffff0000u);
  return r;
}

__device__ __forceinline__ f4 unpack4(ushort4 v) {
  f4 r;
  r[0] = bf2f(v.x); r[1] = bf2f(v.y); r[2] = bf2f(v.z); r[3] = bf2f(v.w);
  return r;
}

__device__ __forceinline__ f4 unp2(uint2 u) {
  f4 r;
  r[0] = bf2f((u16)(u.x & 0xffffu)); r[1] = bf2f((u16)(u.x >> 16));
  r[2] = bf2f((u16)(u.y & 0xffffu)); r[3] = bf2f((u16)(u.y >> 16));
  return r;
}

__device__ __forceinline__ bf8 mkbf8(f4 a, f4 b) {
  union { uint4 u; bf8 v; } c;
  uint2 l = pack4(a), h = pack4(b);
  c.u = make_uint4(l.x, l.y, h.x, h.y);
  return c.v;
}

__device__ __forceinline__ f4 mfma16(bf8 a, bf8 b, f4 c) {
  return __builtin_amdgcn_mfma_f32_16x16x32_bf16(a, b, c, 0, 0, 0);
}

#define ZERO44(acc)                    \
  {                                    \
    f4 z_ = {0.f, 0.f, 0.f, 0.f};      \
    for (int i_ = 0; i_ < 4; ++i_)     \
      for (int j_ = 0; j_ < 4; ++j_)   \
        acc[i_][j_] = z_;              \
  }

// ---------------- transpose-cast fp32 (R,C) -> bf16 (C,R) ----------------
__global__ __launch_bounds__(256) void tcast_k(const float* __restrict__ src,
                                               u16* __restrict__ dst, int R, int C) {
  __shared__ float t[32][33];
  int c0 = blockIdx.x * 32, r0 = blockIdx.y * 32;
  int tx = threadIdx.x & 31, ty = threadIdx.x >> 5;
  #pragma unroll
  for (int i = 0; i < 32; i += 8) {
    int r = r0 + ty + i, c = c0 + tx;
    t[ty + i][tx] = (r < R && c < C) ? src[(size_t)r * C + c] : 0.f;
  }
  __syncthreads();
  #pragma unroll
  for (int i = 0; i < 32; i += 8) {
    int c = c0 + ty + i, r = r0 + tx;
    if (c < C && r < R) dst[(size_t)c * R + r] = f2bf(t[tx][ty + i]);
  }
}

// ---------------- layernorm fp32 -> bf16 (LN1) ----------------
__global__ __launch_bounds__(256) void ln_k(const float* __restrict__ x,
                                            const float* __restrict__ g,
                                            const float* __restrict__ b,
                                            u16* __restrict__ out) {
  int row = blockIdx.x;
  const float* xr = x + (size_t)row * D_;
  float v0 = xr[threadIdx.x], v1 = xr[threadIdx.x + 256], v2 = xr[threadIdx.x + 512];
  float s = v0 + v1 + v2;
  float s2 = v0 * v0 + v1 * v1 + v2 * v2;
  #pragma unroll
  for (int o = 32; o > 0; o >>= 1) {
    s += __shfl_down(s, o, 64);
    s2 += __shfl_down(s2, o, 64);
  }
  __shared__ float a[4], a2[4];
  int wv = threadIdx.x >> 6;
  if ((threadIdx.x & 63) == 0) { a[wv] = s; a2[wv] = s2; }
  __syncthreads();
  s = a[0] + a[1] + a[2] + a[3];
  s2 = a2[0] + a2[1] + a2[2] + a2[3];
  float mean = s * (1.f / 768.f);
  float var = s2 * (1.f / 768.f) - mean * mean;
  float rstd = rsqrtf(var + 1e-5f);
  u16* orow = out + (size_t)row * D_;
  float vv[3] = {v0, v1, v2};
  #pragma unroll
  for (int j = 0; j < 3; ++j) {
    int i = threadIdx.x + j * 256;
    orow[i] = f2bf((vv[j] - mean) * rstd * g[i] + b[i]);
  }
}

// ---------------- x2 = x + O0 + O1; hln = LN(x2) (LN2 fused with partial-O sum) ----------------
__global__ __launch_bounds__(256) void ln2add_k(const float* __restrict__ x,
                                                const u16* __restrict__ O0,
                                                const u16* __restrict__ O1,
                                                const float* __restrict__ g,
                                                const float* __restrict__ b,
                                                float* __restrict__ x2,
                                                u16* __restrict__ out) {
  int row = blockIdx.x;
  const float* xr = x + (size_t)row * D_;
  const u16* o0 = O0 + (size_t)row * D_;
  const u16* o1 = O1 + (size_t)row * D_;
  float vv[3];
  #pragma unroll
  for (int j = 0; j < 3; ++j) {
    int i = threadIdx.x + j * 256;
    vv[j] = xr[i] + bf2f(o0[i]) + bf2f(o1[i]);
  }
  float s = vv[0] + vv[1] + vv[2];
  float s2 = vv[0] * vv[0] + vv[1] * vv[1] + vv[2] * vv[2];
  #pragma unroll
  for (int o = 32; o > 0; o >>= 1) {
    s += __shfl_down(s, o, 64);
    s2 += __shfl_down(s2, o, 64);
  }
  __shared__ float a[4], a2[4];
  int wv = threadIdx.x >> 6;
  if ((threadIdx.x & 63) == 0) { a[wv] = s; a2[wv] = s2; }
  __syncthreads();
  s = a[0] + a[1] + a[2] + a[3];
  s2 = a2[0] + a2[1] + a2[2] + a2[3];
  float mean = s * (1.f / 768.f);
  float var = s2 * (1.f / 768.f) - mean * mean;
  float rstd = rsqrtf(var + 1e-5f);
  float* x2r = x2 + (size_t)row * D_;
  u16* orow = out + (size_t)row * D_;
  #pragma unroll
  for (int j = 0; j < 3; ++j) {
    int i = threadIdx.x + j * 256;
    x2r[i] = vv[j];
    orow[i] = f2bf((vv[j] - mean) * rstd * g[i] + b[i]);
  }
}

// ============ staged 128x128 GEMM core (m97 pattern), K-stride 32 ============
template <int K>
__device__ __forceinline__ void staged_core(const u16* __restrict__ Ab,
                                            const u16* __restrict__ Bb,
                                            u16* As, u16* Bs, f4 acc[4][4]) {
  const int wave = threadIdx.x >> 6, lane = threadIdx.x & 63;
  const int l15 = lane & 15, quad = lane >> 4;
  const int lrow = lane >> 2;
  const int lcol = (lane & 3) * 8;
  const int mw = (wave & 1) * 64, nw = (wave >> 1) * 64;
  for (int k0 = 0; k0 < K; k0 += 32) {
    const u16* ga = Ab + (size_t)(wave * 32 + lrow) * K + k0 + lcol;
    gl_lds16(ga, &As[(wave * 32) * 32]);
    gl_lds16(ga + (size_t)16 * K, &As[(wave * 32 + 16) * 32]);
    const u16* gb = Bb + (size_t)(wave * 32 + lrow) * K + k0 + lcol;
    gl_lds16(gb, &Bs[(wave * 32) * 32]);
    gl_lds16(gb + (size_t)16 * K, &Bs[(wave * 32 + 16) * 32]);
    __syncthreads();
    bf8 a[4], b[4];
    #pragma unroll
    for (int mt = 0; mt < 4; ++mt)
      a[mt] = *reinterpret_cast<const bf8*>(&As[(mw + mt * 16 + l15) * 32 + quad * 8]);
    #pragma unroll
    for (int nt = 0; nt < 4; ++nt)
      b[nt] = *reinterpret_cast<const bf8*>(&Bs[(nw + nt * 16 + l15) * 32 + quad * 8]);
    #pragma unroll
    for (int mt = 0; mt < 4; ++mt)
      #pragma unroll
      for (int nt = 0; nt < 4; ++nt)
        acc[mt][nt] = mfma16(a[mt], b[nt], acc[mt][nt]);
    __syncthreads();
  }
}

// ---------------- QKV GEMM staged ----------------
__global__ __launch_bounds__(256) void gemm_qkv_k(const u16* __restrict__ hln,
                                                  const u16* __restrict__ wT,
                                                  const float* __restrict__ bias,
                                                  u16* __restrict__ Q, u16* __restrict__ Km,
                                                  u16* __restrict__ Vt) {
  __shared__ u16 As[128 * 32], Bs[128 * 32];
  int m0 = blockIdx.y * 128, n0 = blockIdx.x * 128;
  f4 acc[4][4];
  ZERO44(acc);
  staged_core<768>(hln + (size_t)m0 * 768, wT + (size_t)n0 * 768, As, Bs, acc);
  int wave = threadIdx.x >> 6, lane = threadIdx.x & 63, l15 = lane & 15, quad = lane >> 4;
  int mW = m0 + (wave & 1) * 64, nW = n0 + (wave >> 1) * 64;
  #pragma unroll
  for (int mt = 0; mt < 4; ++mt)
    #pragma unroll
    for (int nt = 0; nt < 4; ++nt)
      #pragma unroll
      for (int r = 0; r < 4; ++r) {
        int m = mW + mt * 16 + quad * 4 + r;
        int n = nW + nt * 16 + l15;
        float v = acc[mt][nt][r] + bias[n];
        u16 bv = f2bf(v);
        int b = m >> 11, p = m & 2047;
        int which = n / 768, hn = n % 768;
        int h = hn >> 6, d = hn & 63;
        if (which == 0)
          Q[((size_t)(b * H_ + h) * P_ + p) * HD_ + d] = bv;
        else if (which == 1)
          Km[((size_t)(b * H_ + h) * P_ + p) * HD_ + d] = bv;
        else
          Vt[((size_t)(b * H_ + h) * HD_ + d) * P_ + p] = bv;
      }
}

// ---------------- FC1 GEMM staged + exact GELU ----------------
__global__ __launch_bounds__(256) void gemm_fc1_k(const u16* __restrict__ A,
                                                  const u16* __restrict__ wT,
                                                  const float* __restrict__ bias,
                                                  u16* __restrict__ out) {
  __shared__ u16 As[128 * 32], Bs[128 * 32];
  int m0 = blockIdx.y * 128, n0 = blockIdx.x * 128;
  f4 acc[4][4];
  ZERO44(acc);
  staged_core<768>(A + (size_t)m0 * 768, wT + (size_t)n0 * 768, As, Bs, acc);
  int wave = threadIdx.x >> 6, lane = threadIdx.x & 63, l15 = lane & 15, quad = lane >> 4;
  int mW = m0 + (wave & 1) * 64, nW = n0 + (wave >> 1) * 64;
  #pragma unroll
  for (int mt = 0; mt < 4; ++mt)
    #pragma unroll
    for (int nt = 0; nt < 4; ++nt)
      #pragma unroll
      for (int r = 0; r < 4; ++r) {
        int m = mW + mt * 16 + quad * 4 + r;
        int n = nW + nt * 16 + l15;
        float v = acc[mt][nt][r] + bias[n];
        v = 0.5f * v * (1.f + erff(v * 0.70710678f));
        out[(size_t)m * 3072 + n] = f2bf(v);
      }
}

// ---------------- FC2 GEMM staged (BM=128, BN=64), +bias +residual -> fp32 ----------------
__global__ __launch_bounds__(256) void gemm_fc2_k(const u16* __restrict__ A,
                                                  const u16* __restrict__ wT,
                                                  const float* __restrict__ bias,
                                                  const float* __restrict__ resid,
                                                  float* __restrict__ out) {
  __shared__ u16 As[128 * 32], Bs[64 * 32];
  int wave = threadIdx.x >> 6, lane = threadIdx.x & 63, l15 = lane & 15, quad = lane >> 4;
  int lrow = lane >> 2, lcol = (lane & 3) * 8;
  int m0 = blockIdx.y * 128, n0 = blockIdx.x * 64;
  const u16* Ab = A + (size_t)m0 * 3072;
  const u16* Bb = wT + (size_t)n0 * 3072;
  int mw = (wave & 1) * 64, nw = (wave >> 1) * 32;
  f4 acc[4][2];
  #pragma unroll
  for (int i = 0; i < 4; ++i)
    #pragma unroll
    for (int j = 0; j < 2; ++j) acc[i][j] = f4{0.f, 0.f, 0.f, 0.f};
  for (int k0 = 0; k0 < 3072; k0 += 32) {
    const u16* ga = Ab + (size_t)(wave * 32 + lrow) * 3072 + k0 + lcol;
    gl_lds16(ga, &As[(wave * 32) * 32]);
    gl_lds16(ga + (size_t)16 * 3072, &As[(wave * 32 + 16) * 32]);
    const u16* gb = Bb + (size_t)(wave * 16 + lrow) * 3072 + k0 + lcol;
    gl_lds16(gb, &Bs[(wave * 16) * 32]);
    __syncthreads();
    bf8 a[4], b[2];
    #pragma unroll
    for (int mt = 0; mt < 4; ++mt)
      a[mt] = *reinterpret_cast<const bf8*>(&As[(mw + mt * 16 + l15) * 32 + quad * 8]);
    #pragma unroll
    for (int nt = 0; nt < 2; ++nt)
      b[nt] = *reinterpret_cast<const bf8*>(&Bs[(nw + nt * 16 + l15) * 32 + quad * 8]);
    #pragma unroll
    for (int mt = 0; mt < 4; ++mt)
      #pragma unroll
      for (int nt = 0; nt < 2; ++nt)
        acc[mt][nt] = mfma16(a[mt], b[nt], acc[mt][nt]);
    __syncthreads();
  }
  int mW = m0 + mw, nW = n0 + nw;
  #pragma unroll
  for (int mt = 0; mt < 4; ++mt)
    #pragma unroll
    for (int nt = 0; nt < 2; ++nt)
      #pragma unroll
      for (int r = 0; r < 4; ++r) {
        int m = mW + mt * 16 + quad * 4 + r;
        int n = nW + nt * 16 + l15;
        size_t idx = (size_t)m * 768 + n;
        out[idx] = acc[mt][nt][r] + bias[n] + resid[idx];
      }
}

// ======== fused attention v3: heads-softmax, PT=64 p-rows, q-split=2 ========
// Grid: 256 blocks, 1/CU. flat id: g=id&7 -> XCD; (b,qs)=g so each XCD streams ONE
// (b,qs) K/V sequence (L2-resident). 768 threads = 12 waves = 12 heads.
// Per 32-wide q-tile: wave w computes S^T (q32 x p64) for head w, exp -> E[w] (NOT
// rescaled in place); 512 threads compute R[p][q] = 1/sum_h E; wave w rescales its
// own E[w] fragments in registers for the AV MFMA. Only 2 barriers per tile (E[w]
// has a single writer+reader wave; R is protected by the two barriers).
__global__ __launch_bounds__(768) void attn_fused_k(const u16* __restrict__ Q,
                                                    const u16* __restrict__ Km,
                                                    const u16* __restrict__ Vt,
                                                    u16* __restrict__ O0,
                                                    u16* __restrict__ O1) {
  int id = blockIdx.x;
  int g = id & 7, pt = id >> 3;
  int b = g >> 1, qs = g & 1;
  int w = threadIdx.x >> 6, lane = threadIdx.x & 63, l15 = lane & 15, quad = lane >> 4;
  __shared__ __align__(16) u16 E[12][64][36];  // 55.3 KB, row stride 72B (bank-friendly)
  __shared__ __align__(16) float R[64][32];    // 8 KB reciprocal denominators

  const u16* Qp = Q + ((size_t)(b * H_ + w) * P_ + pt * 64) * HD_;
  const u16* Kbase = Km + ((size_t)(b * H_ + w) * P_ + qs * 1024) * HD_;
  const u16* Vbase = Vt + (size_t)(b * H_ + w) * HD_ * P_ + qs * 1024;

  // Q fragments: 64 p-rows of this wave's head (persist across all q-tiles)
  bf8 qf[4][2];
  #pragma unroll
  for (int nt = 0; nt < 4; ++nt)
    #pragma unroll
    for (int ks = 0; ks < 2; ++ks)
      qf[nt][ks] = *reinterpret_cast<const bf8*>(Qp + (size_t)(nt * 16 + l15) * HD_ + ks * 32 + quad * 8);

  f4 oacc[4][4];  // O^T: d (4x16) x p (4x16)
  ZERO44(oacc);

  for (int qt = 0; qt < 32; ++qt) {
    const u16* Kp = Kbase + (size_t)qt * 32 * HD_;
    // K fragments for this 32-q tile
    bf8 kf[2][2];
    #pragma unroll
    for (int mt = 0; mt < 2; ++mt)
      #pragma unroll
      for (int ks = 0; ks < 2; ++ks)
        kf[mt][ks] = *reinterpret_cast<const bf8*>(Kp + (size_t)(mt * 16 + l15) * HD_ + ks * 32 + quad * 8);
    // V fragments issued early (drain during S/exp)
    bf8 vf[4];
    #pragma unroll
    for (int dt = 0; dt < 4; ++dt)
      vf[dt] = *reinterpret_cast<const bf8*>(Vbase + (size_t)(dt * 16 + l15) * P_ + qt * 32 + quad * 8);
    // S^T + exp -> E[w], one mt (16 q-rows) at a time
    #pragma unroll
    for (int mt = 0; mt < 2; ++mt) {
      f4 s[4];
      #pragma unroll
      for (int nt = 0; nt < 4; ++nt) s[nt] = f4{0.f, 0.f, 0.f, 0.f};
      #pragma unroll
      for (int nt = 0; nt < 4; ++nt) {
        s[nt] = mfma16(kf[mt][0], qf[nt][0], s[nt]);
        s[nt] = mfma16(kf[mt][1], qf[nt][1], s[nt]);
      }
      #pragma unroll
      for (int nt = 0; nt < 4; ++nt) {
        f4 e;
        #pragma unroll
        for (int r = 0; r < 4; ++r) e[r] = __builtin_amdgcn_exp2f(s[nt][r] * EXPC_);
        *reinterpret_cast<uint2*>(&E[w][nt * 16 + l15][mt * 16 + quad * 4]) = pack4(e);
      }
    }
    __syncthreads();
    // R[p][q] = 1 / sum_h E[h][p][q]  (512 threads, one f4 chunk each)
    if (threadIdx.x < 512) {
      int p = threadIdx.x >> 3, qc = (threadIdx.x & 7) * 4;
      f4 sum = {0.f, 0.f, 0.f, 0.f};
      #pragma unroll
      for (int h = 0; h < 12; ++h)
        sum += unpack4(*reinterpret_cast<const ushort4*>(&E[h][p][qc]));
      f4 rc;
      #pragma unroll
      for (int c = 0; c < 4; ++c) rc[c] = __builtin_amdgcn_rcpf(sum[c]);
      *reinterpret_cast<f4*>(&R[p][qc]) = rc;
    }
    __syncthreads();
    // O^T += V^T-frag @ (E[w]*R)-frag
    #pragma unroll
    for (int pi = 0; pi < 4; ++pi) {
      int pp = pi * 16 + l15;
      uint2 e0 = *reinterpret_cast<const uint2*>(&E[w][pp][quad * 8]);
      uint2 e1 = *reinterpret_cast<const uint2*>(&E[w][pp][quad * 8 + 4]);
      f4 r0 = *reinterpret_cast<const f4*>(&R[pp][quad * 8]);
      f4 r1 = *reinterpret_cast<const f4*>(&R[pp][quad * 8 + 4]);
      bf8 af = mkbf8(unp2(e0) * r0, unp2(e1) * r1);
      #pragma unroll
      for (int dt = 0; dt < 4; ++dt)
        oacc[dt][pi] = mfma16(vf[dt], af, oacc[dt][pi]);
    }
    // no trailing barrier: E[w] is written and read only by wave w; R guarded by b1/b2
  }
  __syncthreads();
  // epilogue: stage O^T (bf16) through LDS (alias E as [6][64][72]) in 2 head-phases
  u16(*Os)[64][72] = reinterpret_cast<u16(*)[64][72]>(&E[0][0][0]);
  u16* Op = qs ? O1 : O0;
  #pragma unroll
  for (int hh = 0; hh < 2; ++hh) {
    if (w >= hh * 6 && w < hh * 6 + 6) {
      int wp = w - hh * 6;
      #pragma unroll
      for (int dt = 0; dt < 4; ++dt)
        #pragma unroll
        for (int pi = 0; pi < 4; ++pi)
          *reinterpret_cast<uint2*>(&Os[wp][pi * 16 + l15][dt * 16 + quad * 4]) = pack4(oacc[dt][pi]);
    }
    __syncthreads();
    #pragma unroll
    for (int j = 0; j < 4; ++j) {
      int c = threadIdx.x + j * 768;   // 0..3071
      int p = c / 48, m = c % 48;
      int hp = m >> 3, d = (m & 7) * 8;
      uint4 val = *reinterpret_cast<const uint4*>(&Os[hp][p][d]);
      size_t go = (((size_t)b * P_) + pt * 64 + p) * D_ + (hh * 6 + hp) * 64 + d;
      *reinterpret_cast<uint4*>(Op + go) = val;
    }
    __syncthreads();
  }
}

extern "C" void kernel_launch(void* const* d_in, const int* in_sizes, int n_in,
                              void* d_out, int out_size, void* d_ws, size_t ws_size,
                              hipStream_t stream) {
  const float* x = (const float*)d_in[0];
  const float* ln1w = (const float*)d_in[1];
  const float* ln1b = (const float*)d_in[2];
  const float* wqkv = (const float*)d_in[3];
  const float* bqkv = (const float*)d_in[4];
  const float* ln2w = (const float*)d_in[5];
  const float* ln2b = (const float*)d_in[6];
  const float* wfc1 = (const float*)d_in[7];
  const float* bfc1 = (const float*)d_in[8];
  const float* wfc2 = (const float*)d_in[9];
  const float* bfc2 = (const float*)d_in[10];
  float* out = (float*)d_out;

  char* ws = (char*)d_ws;
  size_t off = 0;
  auto alloc = [&](size_t bytes) -> void* {
    void* p = ws + off;
    off += (bytes + 255) & ~(size_t)255;
    return p;
  };
  u16* hln = (u16*)alloc((size_t)8192 * 768 * 2);
  u16* wqkvT = (u16*)alloc((size_t)2304 * 768 * 2);
  u16* wfc1T = (u16*)alloc((size_t)3072 * 768 * 2);
  u16* wfc2T = (u16*)alloc((size_t)768 * 3072 * 2);
  u16* Qb = (u16*)alloc((size_t)B_ * H_ * P_ * HD_ * 2);
  u16* Kb = (u16*)alloc((size_t)B_ * H_ * P_ * HD_ * 2);
  u16* Vtb = (u16*)alloc((size_t)B_ * H_ * HD_ * P_ * 2);
  float* x2 = (float*)alloc((size_t)8192 * 768 * 4);
  u16* O0 = (u16*)alloc((size_t)8192 * 768 * 2);
  u16* O1 = (u16*)alloc((size_t)8192 * 768 * 2);
  u16* gbuf = (u16*)alloc((size_t)8192 * 3072 * 2);

  tcast_k<<<dim3(72, 24), 256, 0, stream>>>(wqkv, wqkvT, 768, 2304);
  tcast_k<<<dim3(96, 24), 256, 0, stream>>>(wfc1, wfc1T, 768, 3072);
  tcast_k<<<dim3(24, 96), 256, 0, stream>>>(wfc2, wfc2T, 3072, 768);
  ln_k<<<8192, 256, 0, stream>>>(x, ln1w, ln1b, hln);
  gemm_qkv_k<<<dim3(18, 64), 256, 0, stream>>>(hln, wqkvT, bqkv, Qb, Kb, Vtb);
  attn_fused_k<<<256, 768, 0, stream>>>(Qb, Kb, Vtb, O0, O1);
  ln2add_k<<<8192, 256, 0, stream>>>(x, O0, O1, ln2w, ln2b, x2, hln);
  gemm_fc1_k<<<dim3(24, 64), 256, 0, stream>>>(hln, wfc1T, bfc1, gbuf);
  gemm_fc2_k<<<dim3(12, 64), 256, 0, stream>>>(gbuf, wfc2T, bfc2, x2, out);
}